// Round 18
// baseline (252.944 us; speedup 1.0000x reference)
//
#include <hip/hip_runtime.h>

#define NP 16
#define D 768
#define NBLK 512   // ~2 blocks/CU co-resident
#define NTHR 256   // 4 waves
#define RPI 64     // rows per block-iteration (16 per wave = one MFMA tile)
#define DSL 192    // d-slice per wave
#define NM 12      // persistent accumulators

// ws float layout:
//  [0, 6144)                  PTfrag (bf16 B-fragments of normalized protos)
//  [6144, 6144+NBLK*12288)    per-block partial sums
//  [+NBLK*16]                 per-block partial counts
//  [+1]                       ticket counter (int)

typedef short short8 __attribute__((ext_vector_type(8)));
typedef float f32x4 __attribute__((ext_vector_type(4)));

static __device__ __forceinline__ unsigned f2bf_u(float f) {
    unsigned u = __float_as_uint(f);
    u += 0x7FFF + ((u >> 16) & 1);  // RTNE
    return u >> 16;
}
static __device__ __forceinline__ unsigned pack2bf(float lo, float hi) {
    return f2bf_u(lo) | (f2bf_u(hi) << 16);
}

__global__ __launch_bounds__(64) void setup_kernel(const float* __restrict__ protos,
                                                   float* __restrict__ ws, int* __restrict__ ticket) {
    const int p = blockIdx.x, lane = threadIdx.x;
    if (p == 0 && lane == 0) *ticket = 0;
    const float* pr = protos + p * D;
    float v[12];
    float ns = 0.f;
#pragma unroll
    for (int j = 0; j < 12; ++j) {
        v[j] = pr[lane + 64 * j];
        ns = fmaf(v[j], v[j], ns);
    }
#pragma unroll
    for (int m = 1; m < 64; m <<= 1) ns += __shfl_xor(ns, m);
    const float rn = 1.0f / sqrtf(ns);
    // B-fragment scatter (verified r6-r15): Pn[p][c], c=s*32+g*8+jj -> ushort idx (s*64+g*16+p)*8+jj
    unsigned short* ptf = (unsigned short*)ws;
#pragma unroll
    for (int j = 0; j < 12; ++j) {
        const int c = lane + 64 * j;
        const int s = c >> 5, sub = c & 31, g = sub >> 3, jj = sub & 7;
        ptf[(unsigned)((s * 64 + g * 16 + p) * 8 + jj)] = (unsigned short)f2bf_u(v[j] * rn);
    }
}

__global__ __launch_bounds__(NTHR, 2) void fused_kernel(const float* __restrict__ x,
                                                        const float* __restrict__ ws,
                                                        float* __restrict__ gpart,
                                                        float* __restrict__ gcnt,
                                                        int* __restrict__ ticket,
                                                        int nrows, int niter) {
    __shared__ short8 sPT[24 * 64];  // 24 KB proto B-fragments
    __shared__ float rS[RPI];
    __shared__ int aS[RPI];
    __shared__ float C[NP];
    __shared__ int itS[2];  // parity-double-buffered prefetched ticket

    const int tid = threadIdx.x, w = tid >> 6, lane = tid & 63;
    const int r15 = lane & 15, g = lane >> 4;

    {
        const uint4* src = (const uint4*)ws;
        uint4* dst = (uint4*)sPT;
        for (int i = tid; i < 1536; i += NTHR) dst[i] = src[i];
    }
    if (tid < NP) C[tid] = 0.f;
    if (tid == 0) itS[0] = atomicAdd(ticket, 1);
    __syncthreads();

    f32x4 acc[NM];  // persistent segment-sum accumulators (48 VGPR)
#pragma unroll
    for (int m = 0; m < NM; ++m) acc[m] = (f32x4){0.f, 0.f, 0.f, 0.f};

    int p = 0;
    int it = itS[0];
    while (it < niter) {
        // prefetch next ticket into the other parity slot; latency hides under A+B
        if (tid == 0) itS[p ^ 1] = atomicAdd(ticket, 1);
        const int rb = it * RPI;

        // ---------- phase A: sim + norm + argmax for this wave's 16 rows ----------
        {
            const int base = rb + w * 16;
            const int rowc = min(base + r15, nrows - 1);
            const float* xr = x + (size_t)rowc * D + (g << 3);
            const short8* bp = sPT + lane;
            f32x4 se = {0.f, 0.f, 0.f, 0.f}, so = {0.f, 0.f, 0.f, 0.f};
            float nse = 0.f, nso = 0.f;
#pragma unroll
            for (int s = 0; s < 24; s += 2) {
                const float4 f0 = *(const float4*)(xr + s * 32);
                const float4 f1 = *(const float4*)(xr + s * 32 + 4);
                const float4 h0 = *(const float4*)(xr + s * 32 + 32);
                const float4 h1 = *(const float4*)(xr + s * 32 + 36);
                nse = fmaf(f0.x, f0.x, fmaf(f0.y, f0.y, fmaf(f0.z, f0.z, fmaf(f0.w, f0.w, nse))));
                nse = fmaf(f1.x, f1.x, fmaf(f1.y, f1.y, fmaf(f1.z, f1.z, fmaf(f1.w, f1.w, nse))));
                nso = fmaf(h0.x, h0.x, fmaf(h0.y, h0.y, fmaf(h0.z, h0.z, fmaf(h0.w, h0.w, nso))));
                nso = fmaf(h1.x, h1.x, fmaf(h1.y, h1.y, fmaf(h1.z, h1.z, fmaf(h1.w, h1.w, nso))));
                uint4 ae, ao;
                ae.x = pack2bf(f0.x, f0.y); ae.y = pack2bf(f0.z, f0.w);
                ae.z = pack2bf(f1.x, f1.y); ae.w = pack2bf(f1.z, f1.w);
                ao.x = pack2bf(h0.x, h0.y); ao.y = pack2bf(h0.z, h0.w);
                ao.z = pack2bf(h1.x, h1.y); ao.w = pack2bf(h1.z, h1.w);
                se = __builtin_amdgcn_mfma_f32_16x16x32_bf16(
                    __builtin_bit_cast(short8, ae), bp[s * 64], se, 0, 0, 0);
                so = __builtin_amdgcn_mfma_f32_16x16x32_bf16(
                    __builtin_bit_cast(short8, ao), bp[(s + 1) * 64], so, 0, 0, 0);
            }
            f32x4 sc;
#pragma unroll
            for (int r = 0; r < 4; ++r) sc[r] = se[r] + so[r];
            float ns = nse + nso;
            ns += __shfl_xor(ns, 16);
            ns += __shfl_xor(ns, 32);
            const float rn = 1.0f / sqrtf(ns);

            int ar[4];
#pragma unroll
            for (int r = 0; r < 4; ++r) {
                float bv = sc[r];
                int bi = r15;
#pragma unroll
                for (int m = 1; m <= 8; m <<= 1) {
                    const float ov = __shfl_xor(bv, m);
                    const int oi = __shfl_xor(bi, m);
                    if (ov > bv || (ov == bv && oi < bi)) { bv = ov; bi = oi; }
                }
                ar[r] = bi;
            }
            if (r15 == 0) {
#pragma unroll
                for (int r = 0; r < 4; ++r) {
                    aS[w * 16 + g * 4 + r] = ar[r];
                    if (base + g * 4 + r < nrows) atomicAdd(&C[ar[r]], 1.0f);
                }
            }
            if (lane < 16) rS[w * 16 + lane] = (base + lane < nrows) ? rn : 0.f;
        }
        __syncthreads();  // aS/rS ready for all waves

        // ---------- phase B: one-hot MFMA segment-sum over all 64 rows ----------
#pragma unroll
        for (int kc = 0; kc < 2; ++kc) {
            const int nb = kc * 32 + (g << 3);  // this lane's 8-row base (local)
            float rnv[8];
            int an[8];
#pragma unroll
            for (int j = 0; j < 8; ++j) {
                rnv[j] = rS[nb + j];
                an[j] = aS[nb + j];
            }
            uint4 au;
            {
                unsigned t0, t1;
                t0 = (an[0] == r15) ? 0x3F80u : 0u; t1 = (an[1] == r15) ? 0x3F80u : 0u;
                au.x = t0 | (t1 << 16);
                t0 = (an[2] == r15) ? 0x3F80u : 0u; t1 = (an[3] == r15) ? 0x3F80u : 0u;
                au.y = t0 | (t1 << 16);
                t0 = (an[4] == r15) ? 0x3F80u : 0u; t1 = (an[5] == r15) ? 0x3F80u : 0u;
                au.z = t0 | (t1 << 16);
                t0 = (an[6] == r15) ? 0x3F80u : 0u; t1 = (an[7] == r15) ? 0x3F80u : 0u;
                au.w = t0 | (t1 << 16);
            }
            const short8 afrag = __builtin_bit_cast(short8, au);

            const float* rp[8];
#pragma unroll
            for (int j = 0; j < 8; ++j) {
                int rr = rb + nb + j;
                rr = rr < nrows ? rr : nrows - 1;
                rp[j] = x + (size_t)rr * D + w * DSL + r15;
            }
#pragma unroll
            for (int m = 0; m < NM; ++m) {
                float v[8];
#pragma unroll
                for (int j = 0; j < 8; ++j) v[j] = rp[j][m * 16] * rnv[j];  // fp32 rn*x
                uint4 bu;
                bu.x = pack2bf(v[0], v[1]); bu.y = pack2bf(v[2], v[3]);
                bu.z = pack2bf(v[4], v[5]); bu.w = pack2bf(v[6], v[7]);
                acc[m] = __builtin_amdgcn_mfma_f32_16x16x32_bf16(
                    afrag, __builtin_bit_cast(short8, bu), acc[m], 0, 0, 0);
            }
        }
        __syncthreads();  // phase B done with aS/rS; prefetched itS[p^1] visible
        p ^= 1;
        it = itS[p];
    }

    // ---------- flush: non-atomic per-block partials ----------
    // lane holds D[proto = g*4+r][d = w*DSL + m*16 + r15]
    float* gp = gpart + (size_t)blockIdx.x * (NP * D);
#pragma unroll
    for (int m = 0; m < NM; ++m)
#pragma unroll
        for (int r = 0; r < 4; ++r)
            gp[(g * 4 + r) * D + w * DSL + m * 16 + r15] = acc[m][r];
    if (tid < NP) gcnt[blockIdx.x * NP + tid] = C[tid];
}

__global__ __launch_bounds__(256) void finalize_kernel(const float* __restrict__ gpart,
                                                       const float* __restrict__ gcnt,
                                                       float* __restrict__ out) {
    __shared__ float cnt[NP];
    const int tid = threadIdx.x;
    if (tid < NP) {
        float c = 0.f;
        for (int b = 0; b < NBLK; ++b) c += gcnt[b * NP + tid];
        cnt[tid] = c;
    }
    __syncthreads();
    const int i = blockIdx.x * 256 + tid;
    if (i < NP * D) {
        float s = 0.f;
#pragma unroll 8
        for (int b = 0; b < NBLK; ++b) s += gpart[(size_t)b * (NP * D) + i];
        const float c = cnt[i / D];
        out[i] = (c > 0.f) ? s / fmaxf(c, 1.0f) : 0.f;
    }
}

extern "C" void kernel_launch(void* const* d_in, const int* in_sizes, int n_in,
                              void* d_out, int out_size, void* d_ws, size_t ws_size,
                              hipStream_t stream) {
    const float* x = (const float*)d_in[0];
    const float* protos = (const float*)d_in[1];
    float* ws = (float*)d_ws;
    float* out = (float*)d_out;
    const int nrows = in_sizes[0] / D;             // 200000
    const int niter = (nrows + RPI - 1) / RPI;     // 3125 (exact: 3125*64 = 200000)

    float* gpart = ws + 6144;
    float* gcnt = ws + 6144 + (size_t)NBLK * (NP * D);
    int* ticket = (int*)(gcnt + NBLK * NP);

    setup_kernel<<<16, 64, 0, stream>>>(protos, ws, ticket);
    fused_kernel<<<NBLK, NTHR, 0, stream>>>(x, ws, gpart, gcnt, ticket, nrows, niter);
    finalize_kernel<<<(NP * D + 255) / 256, 256, 0, stream>>>(gpart, gcnt, out);
}

// Round 20
// 158.938 us; speedup vs baseline: 1.5915x; 1.5915x over previous
//
#include <hip/hip_runtime.h>

#define NP 16
#define D 768
#define NBLK 256   // 1 block/CU (125 KB LDS), 8 waves/CU
#define NTHR 512   // 8 waves = 4 row-pair teams (K-split phase A)
#define RPI 64     // rows per block-iteration (4 pairs x 16 rows)
#define DSL 96     // d-slice per wave in phase B
#define NM 6       // persistent accumulators

// ws float layout:
//  [0, 6144)                  PTfrag (bf16 B-fragments of normalized protos)
//  [6144, 6144+NBLK*12288)    per-block partial sums
//  [+NBLK*16]                 per-block partial counts

typedef short short8 __attribute__((ext_vector_type(8)));
typedef float f32x4 __attribute__((ext_vector_type(4)));
typedef unsigned u32x2 __attribute__((ext_vector_type(2)));

#define LDS_OFF(ptr) ((unsigned)(size_t)(__attribute__((address_space(3))) const void*)(ptr))

static __device__ __forceinline__ unsigned f2bf_u(float f) {
    unsigned u = __float_as_uint(f);
    u += 0x7FFF + ((u >> 16) & 1);  // RTNE
    return u >> 16;
}
static __device__ __forceinline__ unsigned pack2bf(float lo, float hi) {
    return f2bf_u(lo) | (f2bf_u(hi) << 16);
}

__global__ __launch_bounds__(64) void setup_kernel(const float* __restrict__ protos,
                                                   float* __restrict__ ws) {
    const int p = blockIdx.x, lane = threadIdx.x;
    const float* pr = protos + p * D;
    float v[12];
    float ns = 0.f;
#pragma unroll
    for (int j = 0; j < 12; ++j) {
        v[j] = pr[lane + 64 * j];
        ns = fmaf(v[j], v[j], ns);
    }
#pragma unroll
    for (int m = 1; m < 64; m <<= 1) ns += __shfl_xor(ns, m);
    const float rn = 1.0f / sqrtf(ns);
    // B-fragment scatter (verified r6-r15): Pn[p][c], c=s*32+g*8+jj -> ushort idx (s*64+g*16+p)*8+jj
    unsigned short* ptf = (unsigned short*)ws;
#pragma unroll
    for (int j = 0; j < 12; ++j) {
        const int c = lane + 64 * j;
        const int s = c >> 5, sub = c & 31, g = sub >> 3, jj = sub & 7;
        ptf[(unsigned)((s * 64 + g * 16 + p) * 8 + jj)] = (unsigned short)f2bf_u(v[j] * rn);
    }
}

__global__ __launch_bounds__(NTHR, 2) void fused_kernel(const float* __restrict__ x,
                                                        const float* __restrict__ ws,
                                                        float* __restrict__ gpart,
                                                        float* __restrict__ gcnt,
                                                        int nrows, int niter) {
    __shared__ short8 sPT[24 * 64];          // 24 KB proto B-fragments
    __shared__ unsigned short tileT[49152];  // 96 KB bf16 tile: [q16][cb48][rr4][cc16]
    __shared__ f32x4 simred[4][64];          // 4 KB: K-split partial sims
    __shared__ float normred[4][16];
    __shared__ float rS[RPI];
    __shared__ int aS[RPI];
    __shared__ float C[NP];

    const int tid = threadIdx.x, w = tid >> 6, lane = tid & 63;
    const int r15 = lane & 15, g = lane >> 4;
    const int p = w >> 1, h = w & 1;  // row-pair team, col-half

    {
        const uint4* src = (const uint4*)ws;
        uint4* dst = (uint4*)sPT;
        for (int i = tid; i < 1536; i += NTHR) dst[i] = src[i];
    }
    if (tid < NP) C[tid] = 0.f;
    __syncthreads();

    f32x4 acc[NM];
#pragma unroll
    for (int m = 0; m < NM; ++m) acc[m] = (f32x4){0.f, 0.f, 0.f, 0.f};

    for (int it = blockIdx.x; it < niter; it += NBLK) {
        const int rb = it * RPI;
        const int base = rb + p * 16;

        // ---- phase A: K-split sim (wave h covers cols h*384..+383 of pair p's 16 rows),
        //      writes bf16 tile subtiled for tr_read ----
        const int rowc = min(base + r15, nrows - 1);
        const float* xr = x + (size_t)rowc * D + h * 384 + (g << 3);
        const short8* bp = sPT + lane;
        f32x4 sa = {0.f, 0.f, 0.f, 0.f};
        float nse = 0.f, nso = 0.f;
        const unsigned q = (unsigned)(p * 4 + (r15 >> 2));
        const unsigned rr = (unsigned)(r15 & 3);
        const unsigned cc0 = (unsigned)((g & 1) * 8);
#pragma unroll
        for (int s = 0; s < 12; ++s) {
            const float4 f0 = *(const float4*)(xr + s * 32);
            const float4 f1 = *(const float4*)(xr + s * 32 + 4);
            nse = fmaf(f0.x, f0.x, fmaf(f0.y, f0.y, fmaf(f0.z, f0.z, fmaf(f0.w, f0.w, nse))));
            nso = fmaf(f1.x, f1.x, fmaf(f1.y, f1.y, fmaf(f1.z, f1.z, fmaf(f1.w, f1.w, nso))));
            uint4 au;
            au.x = pack2bf(f0.x, f0.y);
            au.y = pack2bf(f0.z, f0.w);
            au.z = pack2bf(f1.x, f1.y);
            au.w = pack2bf(f1.z, f1.w);
            const unsigned cb = (unsigned)(h * 24 + s * 2 + (g >> 1));
            *(uint4*)&tileT[((q * 48 + cb) * 4 + rr) * 16 + cc0] = au;
            sa = __builtin_amdgcn_mfma_f32_16x16x32_bf16(
                __builtin_bit_cast(short8, au), bp[(h * 12 + s) * 64], sa, 0, 0, 0);
        }
        float ns = nse + nso;
        ns += __shfl_xor(ns, 16);
        ns += __shfl_xor(ns, 32);
        if (h == 1) {
            simred[p][lane] = sa;
            if (lane < 16) normred[p][lane] = ns;
        }
        __syncthreads();  // #1: halves + tile visible

        if (h == 0) {
            const f32x4 o = simred[p][lane];
            f32x4 sc;
#pragma unroll
            for (int r = 0; r < 4; ++r) sc[r] = sa[r] + o[r];
            ns += normred[p][r15];
            const float rn = 1.0f / sqrtf(ns);
            int ar[4];
#pragma unroll
            for (int r = 0; r < 4; ++r) {
                float bv = sc[r];
                int bi = r15;
#pragma unroll
                for (int m = 1; m <= 8; m <<= 1) {
                    const float ov = __shfl_xor(bv, m);
                    const int oi = __shfl_xor(bi, m);
                    if (ov > bv || (ov == bv && oi < bi)) { bv = ov; bi = oi; }
                }
                ar[r] = bi;
            }
            if (r15 == 0) {
#pragma unroll
                for (int r = 0; r < 4; ++r) {
                    aS[p * 16 + g * 4 + r] = ar[r];
                    if (base + g * 4 + r < nrows) atomicAdd(&C[ar[r]], 1.0f);
                }
            }
            if (lane < 16) rS[p * 16 + lane] = (base + lane < nrows) ? rn : 0.f;
        }
        __syncthreads();  // #2: aS/rS ready

        // ---- phase B: rn-weighted one-hot MFMA; B-frag via hardware transpose read ----
        // tr_read lane pattern: lane r15 fetches subtile elems 4*r15..4*r15+3 (byte r15*8);
        // permute network returns column r15 across the 4 rows (m156 model).
#pragma unroll
        for (int kc = 0; kc < 2; ++kc) {
            const int nb = kc * 32 + (g << 3);
            unsigned hb[8];
#pragma unroll
            for (int j = 0; j < 8; ++j) {
                const int an = aS[nb + j];
                const unsigned rb16 = f2bf_u(rS[nb + j]);
                hb[j] = (an == r15) ? rb16 : 0u;
            }
            uint4 au;
            au.x = hb[0] | (hb[1] << 16);
            au.y = hb[2] | (hb[3] << 16);
            au.z = hb[4] | (hb[5] << 16);
            au.w = hb[6] | (hb[7] << 16);
            const short8 afrag = __builtin_bit_cast(short8, au);
            const unsigned qb = (unsigned)(kc * 8 + g * 2);
#pragma unroll
            for (int m = 0; m < NM; ++m) {
                const unsigned cb = (unsigned)(w * 6 + m);
                const unsigned a0 =
                    LDS_OFF(&tileT[((qb + 0) * 48 + cb) * 64 + (unsigned)r15 * 4]);
                const unsigned a1 =
                    LDS_OFF(&tileT[((qb + 1) * 48 + cb) * 64 + (unsigned)r15 * 4]);
                u32x2 t0, t1;
                asm volatile("ds_read_b64_tr_b16 %0, %2\n\t"
                             "ds_read_b64_tr_b16 %1, %3\n\t"
                             "s_waitcnt lgkmcnt(0)"
                             : "=&v"(t0), "=&v"(t1)
                             : "v"(a0), "v"(a1));
                uint4 bu;
                bu.x = t0[0]; bu.y = t0[1]; bu.z = t1[0]; bu.w = t1[1];
                acc[m] = __builtin_amdgcn_mfma_f32_16x16x32_bf16(
                    afrag, __builtin_bit_cast(short8, bu), acc[m], 0, 0, 0);
            }
        }
        __syncthreads();  // #3: tile/aS/rS safe to overwrite next iteration
    }

    // ---- flush: non-atomic per-block partials ----
    // acc[m][r]: proto = g*4+r, d = w*DSL + m*16 + r15
    float* gp = gpart + (size_t)blockIdx.x * (NP * D);
#pragma unroll
    for (int m = 0; m < NM; ++m)
#pragma unroll
        for (int r = 0; r < 4; ++r)
            gp[(g * 4 + r) * D + w * DSL + m * 16 + r15] = acc[m][r];
    if (tid < NP) gcnt[blockIdx.x * NP + tid] = C[tid];
}

__global__ __launch_bounds__(256) void finalize_kernel(const float* __restrict__ gpart,
                                                       const float* __restrict__ gcnt,
                                                       float* __restrict__ out) {
    __shared__ float cnt[NP];
    const int tid = threadIdx.x;
    if (tid < NP) {
        float c = 0.f;
        for (int b = 0; b < NBLK; ++b) c += gcnt[b * NP + tid];
        cnt[tid] = c;
    }
    __syncthreads();
    const int i = blockIdx.x * 256 + tid;
    if (i < NP * D) {
        float s = 0.f;
#pragma unroll 8
        for (int b = 0; b < NBLK; ++b) s += gpart[(size_t)b * (NP * D) + i];
        const float c = cnt[i / D];
        out[i] = (c > 0.f) ? s / fmaxf(c, 1.0f) : 0.f;
    }
}

extern "C" void kernel_launch(void* const* d_in, const int* in_sizes, int n_in,
                              void* d_out, int out_size, void* d_ws, size_t ws_size,
                              hipStream_t stream) {
    const float* x = (const float*)d_in[0];
    const float* protos = (const float*)d_in[1];
    float* ws = (float*)d_ws;
    float* out = (float*)d_out;
    const int nrows = in_sizes[0] / D;             // 200000
    const int niter = (nrows + RPI - 1) / RPI;     // 3125 (exact: 3125*64 = 200000)

    float* gpart = ws + 6144;
    float* gcnt = ws + 6144 + (size_t)NBLK * (NP * D);

    setup_kernel<<<16, 64, 0, stream>>>(protos, ws);
    fused_kernel<<<NBLK, NTHR, 0, stream>>>(x, ws, gpart, gcnt, nrows, niter);
    finalize_kernel<<<(NP * D + 255) / 256, 256, 0, stream>>>(gpart, gcnt, out);
}